// Round 5
// baseline (352.046 us; speedup 1.0000x reference)
//
#include <hip/hip_runtime.h>
#include <cmath>

#define BB 8
#define CC 256
#define CQ 64
#define NN 4096
constexpr float INV_N = 1.0f / 4096.0f;   // 2^-12: exact, folded into epilogue

typedef __attribute__((ext_vector_type(8))) short short8;
typedef __attribute__((ext_vector_type(4))) short short4v;
typedef __attribute__((ext_vector_type(4))) float float4v;

__device__ __forceinline__ short f2bf(float f) {
  union { float f; unsigned u; } x; x.f = f;
  unsigned r = x.u + 0x7fffu + ((x.u >> 16) & 1u);
  return (short)(r >> 16);
}

// ---------------------------------------------------------------------------
// One-time fp32 -> bf16 conversion of all conv weights into workspace.
// ---------------------------------------------------------------------------
__global__ void wconv_kernel(const float* __restrict__ wq,
                             const float* __restrict__ wk,
                             const float* __restrict__ wv,
                             const float* __restrict__ wg,
                             short* __restrict__ wqb, short* __restrict__ wkb,
                             short* __restrict__ wvb, short* __restrict__ wgb) {
  const int t = blockIdx.x * 256 + threadIdx.x;
  const float* src;
  short* dst;
  int idx;
  if (t < 4096)        { src = wq; dst = wqb; idx = t; }
  else if (t < 8192)   { src = wk; dst = wkb; idx = t - 4096; }
  else if (t < 24576)  { src = wv; dst = wvb; idx = t - 8192; }
  else                 { src = wg; dst = wgb; idx = t - 24576; }
  const float4 v = *reinterpret_cast<const float4*>(&src[(size_t)idx * 4]);
  short4v o;
  o[0] = f2bf(v.x); o[1] = f2bf(v.y); o[2] = f2bf(v.z); o[3] = f2bf(v.w);
  *reinterpret_cast<short4v*>(&dst[(size_t)idx * 4]) = o;
}

// ---------------------------------------------------------------------------
// Fused q/k/v conv1x1, v5 — UNCHANGED from round 4 (isolating attn change).
// ---------------------------------------------------------------------------
__global__ __launch_bounds__(256, 2) void qkv_kernel(
    const float* __restrict__ X,
    const short* __restrict__ wqb, const float* __restrict__ bq,
    const short* __restrict__ wkb, const float* __restrict__ bk,
    const short* __restrict__ wvb, const float* __restrict__ bv,
    short* __restrict__ qt, short* __restrict__ kt, short* __restrict__ vbf) {
  __shared__ short xt[64 * 264];   // 33792 B; Os buffers alias after frag load
  const int tid = threadIdx.x;
  const int wid = tid >> 6;
  const int lane = tid & 63, quad = lane >> 4, l16 = lane & 15;
  const int b = blockIdx.x, n0 = blockIdx.y * 64;

  float4 xb[16];
#pragma unroll
  for (int p = 0; p < 16; ++p) {
    const int idx = p * 256 + tid;
    const int c = idx >> 4;
    const int n4 = (idx & 15) * 4;
    xb[p] = *reinterpret_cast<const float4*>(
        &X[((size_t)b * CC + c) * NN + n0 + n4]);
  }
#pragma unroll
  for (int p = 0; p < 16; ++p) {
    const int idx = p * 256 + tid;
    const int c = idx >> 4;
    const int n4 = (idx & 15) * 4;
    xt[(n4 + 0) * 264 + c] = f2bf(xb[p].x);
    xt[(n4 + 1) * 264 + c] = f2bf(xb[p].y);
    xt[(n4 + 2) * 264 + c] = f2bf(xb[p].z);
    xt[(n4 + 3) * 264 + c] = f2bf(xb[p].w);
  }
  __syncthreads();

  short8 bfr[8][4];
#pragma unroll
  for (int kk = 0; kk < 8; ++kk)
#pragma unroll
    for (int tm = 0; tm < 4; ++tm)
      bfr[kk][tm] = *reinterpret_cast<const short8*>(
          &xt[(tm * 16 + l16) * 264 + kk * 32 + quad * 8]);
  __syncthreads();   // xt dead; Os aliasing now safe

  short* Os0 = xt;          // [64 o][72 n]
  short* Os1 = xt + 4608;

  for (int ch = 0; ch < 6; ++ch) {
    const short* W; const float* bias; int obase;
    if (ch == 0)      { W = wqb; bias = bq; obase = 0; }
    else if (ch == 1) { W = wkb; bias = bk; obase = 0; }
    else { W = wvb + (size_t)(ch - 2) * 64 * CC; bias = bv + (ch - 2) * 64; obase = (ch - 2) * 64; }

    const short* wrow = &W[(size_t)(wid * 16 + l16) * CC + quad * 8];
    short8 wf[8];
#pragma unroll
    for (int kk = 0; kk < 8; ++kk)
      wf[kk] = *reinterpret_cast<const short8*>(wrow + kk * 32);

    float4v acc[4];
#pragma unroll
    for (int tm = 0; tm < 4; ++tm) acc[tm] = float4v{0.f, 0.f, 0.f, 0.f};
#pragma unroll
    for (int kk = 0; kk < 8; ++kk)
#pragma unroll
      for (int tm = 0; tm < 4; ++tm)
        acc[tm] = __builtin_amdgcn_mfma_f32_16x16x32_bf16(wf[kk], bfr[kk][tm], acc[tm], 0, 0, 0);

    if (ch < 2) {
      short* dst = (ch == 0) ? qt : kt;
#pragma unroll
      for (int tm = 0; tm < 4; ++tm) {
        short4v pk;
#pragma unroll
        for (int r = 0; r < 4; ++r)
          pk[r] = f2bf(acc[tm][r] + bias[wid * 16 + quad * 4 + r]);
        *reinterpret_cast<short4v*>(
            &dst[((size_t)b * NN + n0 + tm * 16 + l16) * 64 + wid * 16 + quad * 4]) = pk;
      }
    } else {
      short* Os = (ch & 1) ? Os1 : Os0;
#pragma unroll
      for (int tm = 0; tm < 4; ++tm)
#pragma unroll
        for (int r = 0; r < 4; ++r)
          Os[(wid * 16 + quad * 4 + r) * 72 + tm * 16 + l16] =
              f2bf(acc[tm][r] + bias[wid * 16 + quad * 4 + r]);
      __syncthreads();
      const int o = tid >> 2, ng = (tid & 3) * 16;
      const short8 s0 = *reinterpret_cast<const short8*>(&Os[o * 72 + ng]);
      const short8 s1 = *reinterpret_cast<const short8*>(&Os[o * 72 + ng + 8]);
      short* vp = &vbf[((size_t)b * CC + obase + o) * NN + n0 + ng];
      *reinterpret_cast<short8*>(vp) = s0;
      *reinterpret_cast<short8*>(vp + 8) = s1;
    }
  }
}

// ---------------------------------------------------------------------------
// Fused MFMA attention + gamma conv, v7 — TRAFFIC-HALVING experiment:
//  - m-tile 128, 512 threads (8 waves), grid (B, 32) = 256 blocks, 1/CU.
//    Each block reads all of vbf[b] (2 MB); halving #blocks halves total
//    V cache traffic — the quantity that has predicted attn time in ALL
//    rounds so far (r2: 2x traffic -> 2x time; r3/r4: same traffic -> null).
//  - per-wave shape stays r1-like (40 MFMA/iter): wave wid owns m-16-group
//    wid for QK and c-slice [wid*32, wid*32+32) for PV.
//  - same software-pipeline order as r4 (QK(it+1), PV(it), elu(it+1)).
//  - T5: s_setprio(1) around the MFMA cluster (8 waves now phase-split).
//  - epilogue gamma conv in two m-halves (Outs [64][264] fits Es space).
// ---------------------------------------------------------------------------
__global__ __launch_bounds__(512, 2) void attn_kernel(
    const short* __restrict__ qt, const short* __restrict__ kt,
    const short* __restrict__ vbf, const short* __restrict__ wgb,
    const float* __restrict__ bg, float* __restrict__ out) {
  __shared__ short smem[18432];   // 36864 B
  short* Es0 = smem;              // [128 m][72 n] = 9216 shorts
  short* Es1 = smem + 9216;
  short* Outs = smem;             // [64 m][264 c] epilogue alias, per m-half

  const int tid = threadIdx.x;
  const int wid = tid >> 6;                 // 0..7
  const int lane = tid & 63, quad = lane >> 4, l16 = lane & 15;
  const int b = blockIdx.x, m0 = blockIdx.y * 128;

  // K frags: wave's m-16-group (tm == wid)
  short8 bkf[2];
#pragma unroll
  for (int kk = 0; kk < 2; ++kk)
    bkf[kk] = *reinterpret_cast<const short8*>(
        &kt[((size_t)b * NN + m0 + wid * 16 + l16) * 64 + kk * 32 + quad * 8]);

  const short* qb = &qt[((size_t)b * NN + l16) * 64 + quad * 8];
  const short* vrow[2];
#pragma unroll
  for (int tc = 0; tc < 2; ++tc)
    vrow[tc] = &vbf[((size_t)b * CC + wid * 32 + tc * 16 + l16) * NN + quad * 8];

  float4v acc[2][8];
#pragma unroll
  for (int i = 0; i < 2; ++i)
#pragma unroll
    for (int j = 0; j < 8; ++j) acc[i][j] = float4v{0.f, 0.f, 0.f, 0.f};

  // ---- prologue: QK(0) -> Es0 ----
#pragma unroll
  for (int ng = 0; ng < 4; ++ng) {
    const short8 a0 = *reinterpret_cast<const short8*>(qb + (size_t)(ng * 16) * 64);
    const short8 a1 = *reinterpret_cast<const short8*>(qb + (size_t)(ng * 16) * 64 + 32);
    float4v t = {0.f, 0.f, 0.f, 0.f};
    t = __builtin_amdgcn_mfma_f32_16x16x32_bf16(a0, bkf[0], t, 0, 0, 0);
    t = __builtin_amdgcn_mfma_f32_16x16x32_bf16(a1, bkf[1], t, 0, 0, 0);
    short4v pk;
#pragma unroll
    for (int r = 0; r < 4; ++r) {
      float sv = t[r];
      sv = (sv > 0.f) ? sv : (__expf(sv) - 1.f);
      pk[r] = f2bf(sv);
    }
    *reinterpret_cast<short4v*>(
        &Es0[(wid * 16 + l16) * 72 + ng * 16 + quad * 4]) = pk;
  }
  __syncthreads();

  for (int it = 0; it < 64; ++it) {
    short* Esr = (it & 1) ? Es1 : Es0;
    short* Esw = (it & 1) ? Es0 : Es1;
    const int nb = it * 64;

    // loads for this segment
    short8 av[2][2];
#pragma unroll
    for (int tc = 0; tc < 2; ++tc) {
      av[tc][0] = *reinterpret_cast<const short8*>(vrow[tc] + nb);
      av[tc][1] = *reinterpret_cast<const short8*>(vrow[tc] + nb + 32);
    }
    short8 aq[4][2];
    if (it < 63) {
#pragma unroll
      for (int ng = 0; ng < 4; ++ng) {
        const size_t qoff = (size_t)((it + 1) * 64 + ng * 16) * 64;
        aq[ng][0] = *reinterpret_cast<const short8*>(qb + qoff);
        aq[ng][1] = *reinterpret_cast<const short8*>(qb + qoff + 32);
      }
    }

    __builtin_amdgcn_s_setprio(1);
    // QK^T(it+1) — independent of PV(it)
    float4v s[4];
    if (it < 63) {
#pragma unroll
      for (int ng = 0; ng < 4; ++ng) {
        float4v t = {0.f, 0.f, 0.f, 0.f};
        t = __builtin_amdgcn_mfma_f32_16x16x32_bf16(aq[ng][0], bkf[0], t, 0, 0, 0);
        t = __builtin_amdgcn_mfma_f32_16x16x32_bf16(aq[ng][1], bkf[1], t, 0, 0, 0);
        s[ng] = t;
      }
    }
    // PV(it): acc[c-slice][all 8 m-tiles]
#pragma unroll
    for (int tm = 0; tm < 8; ++tm) {
      const short8 be0 = *reinterpret_cast<const short8*>(
          &Esr[(tm * 16 + l16) * 72 + quad * 8]);
      const short8 be1 = *reinterpret_cast<const short8*>(
          &Esr[(tm * 16 + l16) * 72 + 32 + quad * 8]);
#pragma unroll
      for (int tc = 0; tc < 2; ++tc) {
        acc[tc][tm] = __builtin_amdgcn_mfma_f32_16x16x32_bf16(av[tc][0], be0, acc[tc][tm], 0, 0, 0);
        acc[tc][tm] = __builtin_amdgcn_mfma_f32_16x16x32_bf16(av[tc][1], be1, acc[tc][tm], 0, 0, 0);
      }
    }
    __builtin_amdgcn_s_setprio(0);

    // elu(it+1) -> Es[(it+1)&1]
    if (it < 63) {
#pragma unroll
      for (int ng = 0; ng < 4; ++ng) {
        short4v pk;
#pragma unroll
        for (int r = 0; r < 4; ++r) {
          float sv = s[ng][r];
          sv = (sv > 0.f) ? sv : (__expf(sv) - 1.f);
          pk[r] = f2bf(sv);
        }
        *reinterpret_cast<short4v*>(
            &Esw[(wid * 16 + l16) * 72 + ng * 16 + quad * 4]) = pk;
      }
    }
    __syncthreads();
  }

  // ---- epilogue: gamma conv via MFMA, two m-halves (INV_N applied, exact) ----
#pragma unroll
  for (int mh = 0; mh < 2; ++mh) {
#pragma unroll
    for (int tmh = 0; tmh < 4; ++tmh)
#pragma unroll
      for (int tc = 0; tc < 2; ++tc) {
        short4v pk;
#pragma unroll
        for (int r = 0; r < 4; ++r)
          pk[r] = f2bf(acc[tc][mh * 4 + tmh][r] * INV_N);
        *reinterpret_cast<short4v*>(
            &Outs[(tmh * 16 + l16) * 264 + wid * 32 + tc * 16 + quad * 4]) = pk;
      }
    __syncthreads();

    float4v acg[2][4];
#pragma unroll
    for (int i = 0; i < 2; ++i)
#pragma unroll
      for (int j = 0; j < 4; ++j) acg[i][j] = float4v{0.f, 0.f, 0.f, 0.f};

    for (int ks8 = 0; ks8 < 8; ++ks8) {
      short8 ag[2];
#pragma unroll
      for (int to = 0; to < 2; ++to)
        ag[to] = *reinterpret_cast<const short8*>(
            &wgb[(size_t)(wid * 32 + to * 16 + l16) * CC + ks8 * 32 + quad * 8]);
      short8 bo[4];
#pragma unroll
      for (int tmh = 0; tmh < 4; ++tmh)
        bo[tmh] = *reinterpret_cast<const short8*>(
            &Outs[(tmh * 16 + l16) * 264 + ks8 * 32 + quad * 8]);
#pragma unroll
      for (int to = 0; to < 2; ++to)
#pragma unroll
        for (int tmh = 0; tmh < 4; ++tmh)
          acg[to][tmh] =
              __builtin_amdgcn_mfma_f32_16x16x32_bf16(ag[to], bo[tmh], acg[to][tmh], 0, 0, 0);
    }

#pragma unroll
    for (int to = 0; to < 2; ++to) {
#pragma unroll
      for (int r = 0; r < 4; ++r) {
        const int o = wid * 32 + to * 16 + quad * 4 + r;
        const float bgv = bg[o];
#pragma unroll
        for (int tmh = 0; tmh < 4; ++tmh) {
          out[((size_t)b * CC + o) * NN + m0 + mh * 64 + tmh * 16 + l16] =
              acg[to][tmh][r] + bgv;
        }
      }
    }
    __syncthreads();   // protect next half's Outs writes against these reads
  }
}

// ---------------------------------------------------------------------------
extern "C" void kernel_launch(void* const* d_in, const int* in_sizes, int n_in,
                              void* d_out, int out_size, void* d_ws,
                              size_t ws_size, hipStream_t stream) {
  const float* x  = (const float*)d_in[0];
  const float* wq = (const float*)d_in[1];
  const float* bq = (const float*)d_in[2];
  const float* wk = (const float*)d_in[3];
  const float* bk = (const float*)d_in[4];
  const float* wv = (const float*)d_in[5];
  const float* bv = (const float*)d_in[6];
  const float* wg = (const float*)d_in[7];
  const float* bg = (const float*)d_in[8];
  float* out = (float*)d_out;

  short* qt  = (short*)d_ws;                     // [B][N][64] bf16, 4 MB
  short* kt  = qt + (size_t)BB * NN * CQ;        // 4 MB
  short* vbf = kt + (size_t)BB * NN * CQ;        // [B][C][N] bf16, 16 MB
  short* wqb = vbf + (size_t)BB * CC * NN;       // bf16 weights, 320 KB total
  short* wkb = wqb + (size_t)CQ * CC;
  short* wvb = wkb + (size_t)CQ * CC;
  short* wgb = wvb + (size_t)CC * CC;

  wconv_kernel<<<dim3(160), 256, 0, stream>>>(wq, wk, wv, wg, wqb, wkb, wvb, wgb);
  qkv_kernel<<<dim3(BB, NN / 64), 256, 0, stream>>>(x, wqb, bq, wkb, bk, wvb, bv,
                                                    qt, kt, vbf);
  attn_kernel<<<dim3(BB, NN / 128), 512, 0, stream>>>(qt, kt, vbf, wgb, bg, out);
}

// Round 6
// 269.995 us; speedup vs baseline: 1.3039x; 1.3039x over previous
//
#include <hip/hip_runtime.h>
#include <cmath>

#define BB 8
#define CC 256
#define CQ 64
#define NN 4096
constexpr float INV_N = 1.0f / 4096.0f;   // 2^-12: exact, folded into epilogue

typedef __attribute__((ext_vector_type(8))) short short8;
typedef __attribute__((ext_vector_type(4))) short short4v;
typedef __attribute__((ext_vector_type(4))) float float4v;

__device__ __forceinline__ short f2bf(float f) {
  union { float f; unsigned u; } x; x.f = f;
  unsigned r = x.u + 0x7fffu + ((x.u >> 16) & 1u);
  return (short)(r >> 16);
}

// Barrier that does NOT drain vmcnt: LDS (Es) ordering only. Prefetched
// global loads stay in flight across it; their consumers get compiler-
// inserted counted vmcnt waits. sched_barrier stops hipcc migrating ops
// across the asm (rule #18).
__device__ __forceinline__ void lds_barrier() {
  asm volatile("s_waitcnt lgkmcnt(0)" ::: "memory");
  __builtin_amdgcn_s_barrier();
  __builtin_amdgcn_sched_barrier(0);
}

// ---------------------------------------------------------------------------
// One-time fp32 -> bf16 conversion of all conv weights into workspace.
// ---------------------------------------------------------------------------
__global__ void wconv_kernel(const float* __restrict__ wq,
                             const float* __restrict__ wk,
                             const float* __restrict__ wv,
                             const float* __restrict__ wg,
                             short* __restrict__ wqb, short* __restrict__ wkb,
                             short* __restrict__ wvb, short* __restrict__ wgb) {
  const int t = blockIdx.x * 256 + threadIdx.x;
  const float* src;
  short* dst;
  int idx;
  if (t < 4096)        { src = wq; dst = wqb; idx = t; }
  else if (t < 8192)   { src = wk; dst = wkb; idx = t - 4096; }
  else if (t < 24576)  { src = wv; dst = wvb; idx = t - 8192; }
  else                 { src = wg; dst = wgb; idx = t - 24576; }
  const float4 v = *reinterpret_cast<const float4*>(&src[(size_t)idx * 4]);
  short4v o;
  o[0] = f2bf(v.x); o[1] = f2bf(v.y); o[2] = f2bf(v.z); o[3] = f2bf(v.w);
  *reinterpret_cast<short4v*>(&dst[(size_t)idx * 4]) = o;
}

// ---------------------------------------------------------------------------
// Fused q/k/v conv1x1, v5 — UNCHANGED from round 4 (isolating attn change).
// ---------------------------------------------------------------------------
__global__ __launch_bounds__(256, 2) void qkv_kernel(
    const float* __restrict__ X,
    const short* __restrict__ wqb, const float* __restrict__ bq,
    const short* __restrict__ wkb, const float* __restrict__ bk,
    const short* __restrict__ wvb, const float* __restrict__ bv,
    short* __restrict__ qt, short* __restrict__ kt, short* __restrict__ vbf) {
  __shared__ short xt[64 * 264];   // 33792 B; Os buffers alias after frag load
  const int tid = threadIdx.x;
  const int wid = tid >> 6;
  const int lane = tid & 63, quad = lane >> 4, l16 = lane & 15;
  const int b = blockIdx.x, n0 = blockIdx.y * 64;

  float4 xb[16];
#pragma unroll
  for (int p = 0; p < 16; ++p) {
    const int idx = p * 256 + tid;
    const int c = idx >> 4;
    const int n4 = (idx & 15) * 4;
    xb[p] = *reinterpret_cast<const float4*>(
        &X[((size_t)b * CC + c) * NN + n0 + n4]);
  }
#pragma unroll
  for (int p = 0; p < 16; ++p) {
    const int idx = p * 256 + tid;
    const int c = idx >> 4;
    const int n4 = (idx & 15) * 4;
    xt[(n4 + 0) * 264 + c] = f2bf(xb[p].x);
    xt[(n4 + 1) * 264 + c] = f2bf(xb[p].y);
    xt[(n4 + 2) * 264 + c] = f2bf(xb[p].z);
    xt[(n4 + 3) * 264 + c] = f2bf(xb[p].w);
  }
  __syncthreads();

  short8 bfr[8][4];
#pragma unroll
  for (int kk = 0; kk < 8; ++kk)
#pragma unroll
    for (int tm = 0; tm < 4; ++tm)
      bfr[kk][tm] = *reinterpret_cast<const short8*>(
          &xt[(tm * 16 + l16) * 264 + kk * 32 + quad * 8]);
  __syncthreads();   // xt dead; Os aliasing now safe

  short* Os0 = xt;          // [64 o][72 n]
  short* Os1 = xt + 4608;

  for (int ch = 0; ch < 6; ++ch) {
    const short* W; const float* bias; int obase;
    if (ch == 0)      { W = wqb; bias = bq; obase = 0; }
    else if (ch == 1) { W = wkb; bias = bk; obase = 0; }
    else { W = wvb + (size_t)(ch - 2) * 64 * CC; bias = bv + (ch - 2) * 64; obase = (ch - 2) * 64; }

    const short* wrow = &W[(size_t)(wid * 16 + l16) * CC + quad * 8];
    short8 wf[8];
#pragma unroll
    for (int kk = 0; kk < 8; ++kk)
      wf[kk] = *reinterpret_cast<const short8*>(wrow + kk * 32);

    float4v acc[4];
#pragma unroll
    for (int tm = 0; tm < 4; ++tm) acc[tm] = float4v{0.f, 0.f, 0.f, 0.f};
#pragma unroll
    for (int kk = 0; kk < 8; ++kk)
#pragma unroll
      for (int tm = 0; tm < 4; ++tm)
        acc[tm] = __builtin_amdgcn_mfma_f32_16x16x32_bf16(wf[kk], bfr[kk][tm], acc[tm], 0, 0, 0);

    if (ch < 2) {
      short* dst = (ch == 0) ? qt : kt;
#pragma unroll
      for (int tm = 0; tm < 4; ++tm) {
        short4v pk;
#pragma unroll
        for (int r = 0; r < 4; ++r)
          pk[r] = f2bf(acc[tm][r] + bias[wid * 16 + quad * 4 + r]);
        *reinterpret_cast<short4v*>(
            &dst[((size_t)b * NN + n0 + tm * 16 + l16) * 64 + wid * 16 + quad * 4]) = pk;
      }
    } else {
      short* Os = (ch & 1) ? Os1 : Os0;
#pragma unroll
      for (int tm = 0; tm < 4; ++tm)
#pragma unroll
        for (int r = 0; r < 4; ++r)
          Os[(wid * 16 + quad * 4 + r) * 72 + tm * 16 + l16] =
              f2bf(acc[tm][r] + bias[wid * 16 + quad * 4 + r]);
      __syncthreads();
      const int o = tid >> 2, ng = (tid & 3) * 16;
      const short8 s0 = *reinterpret_cast<const short8*>(&Os[o * 72 + ng]);
      const short8 s1 = *reinterpret_cast<const short8*>(&Os[o * 72 + ng + 8]);
      short* vp = &vbf[((size_t)b * CC + obase + o) * NN + n0 + ng];
      *reinterpret_cast<short8*>(vp) = s0;
      *reinterpret_cast<short8*>(vp + 8) = s1;
    }
  }
}

// ---------------------------------------------------------------------------
// Fused MFMA attention + gamma conv, v8 = r4's pipeline + NON-DRAINING
// barriers in the main loop:
//   __syncthreads() emits s_waitcnt vmcnt(0) lgkmcnt(0) + s_barrier — it
//   drained the 10 in-flight prefetch loads EVERY segment (the invariant
//   ~3600 cy/iter stall r2-r5 could not move). Only Es (LDS) needs barrier
//   ordering -> lgkmcnt(0)-only barrier; global q/v loads now stay in
//   flight across segments with compiler-counted vmcnt on consumption.
// Everything else identical to round 4. grid (B, 64), 256 thr, 2 blocks/CU.
// ---------------------------------------------------------------------------
__global__ __launch_bounds__(256, 2) void attn_kernel(
    const short* __restrict__ qt, const short* __restrict__ kt,
    const short* __restrict__ vbf, const short* __restrict__ wgb,
    const float* __restrict__ bg, float* __restrict__ out) {
  __shared__ short smem[16896];   // 33792 B
  short* Es0 = smem;              // [64 m][72 n]
  short* Es1 = smem + 4608;
  short* Outs = smem;             // [64 m][264 c] epilogue alias

  const int tid = threadIdx.x;
  const int wid = tid >> 6;
  const int lane = tid & 63, quad = lane >> 4, l16 = lane & 15;
  const int b = blockIdx.x, m0 = blockIdx.y * 64;

  // k fragments: resident in registers for the whole kernel
  short8 bkf[4][2];
#pragma unroll
  for (int tm = 0; tm < 4; ++tm)
#pragma unroll
    for (int kk = 0; kk < 2; ++kk)
      bkf[tm][kk] = *reinterpret_cast<const short8*>(
          &kt[((size_t)b * NN + m0 + tm * 16 + l16) * 64 + kk * 32 + quad * 8]);

  const short* qp = &qt[((size_t)b * NN + wid * 16 + l16) * 64 + quad * 8];
  const short* vrow[4];
#pragma unroll
  for (int tc = 0; tc < 4; ++tc)
    vrow[tc] = &vbf[((size_t)b * CC + wid * 64 + tc * 16 + l16) * NN + quad * 8];

  float4v acc[4][4];
#pragma unroll
  for (int i = 0; i < 4; ++i)
#pragma unroll
    for (int j = 0; j < 4; ++j) acc[i][j] = float4v{0.f, 0.f, 0.f, 0.f};

  // ---- prologue: v(0), q(0); QK(0)+elu -> Es0; preload q(1) ----
  short8 avA[4][2], avB[4][2];
#pragma unroll
  for (int tc = 0; tc < 4; ++tc) {
    avA[tc][0] = *reinterpret_cast<const short8*>(vrow[tc]);
    avA[tc][1] = *reinterpret_cast<const short8*>(vrow[tc] + 32);
  }
  short8 aqA0 = *reinterpret_cast<const short8*>(qp + (size_t)1 * 4096);
  short8 aqA1 = *reinterpret_cast<const short8*>(qp + (size_t)1 * 4096 + 32);
  short8 aqB0, aqB1;
  {
    const short8 aq0 = *reinterpret_cast<const short8*>(qp);
    const short8 aq1 = *reinterpret_cast<const short8*>(qp + 32);
#pragma unroll
    for (int tm = 0; tm < 4; ++tm) {
      float4v t = {0.f, 0.f, 0.f, 0.f};
      t = __builtin_amdgcn_mfma_f32_16x16x32_bf16(aq0, bkf[tm][0], t, 0, 0, 0);
      t = __builtin_amdgcn_mfma_f32_16x16x32_bf16(aq1, bkf[tm][1], t, 0, 0, 0);
      short4v pk;
#pragma unroll
      for (int r = 0; r < 4; ++r) {
        float sv = t[r];
        sv = (sv > 0.f) ? sv : (__expf(sv) - 1.f);
        pk[r] = f2bf(sv);
      }
      *reinterpret_cast<short4v*>(
          &Es0[(tm * 16 + l16) * 72 + wid * 16 + quad * 4]) = pk;
    }
  }
  lds_barrier();

  // avc = v(it) [consumed by PV(it)]; avn <- v(it+1)
  // aqc = q(it+1) [consumed by QK(it+1)]; aqn <- q(it+2)
  auto seg = [&](int it, short8 (&avc)[4][2], short8 (&avn)[4][2],
                 short8& aqc0, short8& aqc1, short8& aqn0, short8& aqn1) {
    const int nb1 = (it + 1) * 64;
#pragma unroll
    for (int tc = 0; tc < 4; ++tc) {
      avn[tc][0] = *reinterpret_cast<const short8*>(vrow[tc] + nb1);
      avn[tc][1] = *reinterpret_cast<const short8*>(vrow[tc] + nb1 + 32);
    }
    // q(it+2); trailing reads spill into kt region — allocated, unused
    aqn0 = *reinterpret_cast<const short8*>(qp + (size_t)(it + 2) * 4096);
    aqn1 = *reinterpret_cast<const short8*>(qp + (size_t)(it + 2) * 4096 + 32);

    short* Esr = (it & 1) ? Es1 : Es0;
    short* Esw = (it & 1) ? Es0 : Es1;

    // QK^T(it+1) — independent of PV(it); results consumed only after PV
    float4v s[4];
    if (it < 63) {
#pragma unroll
      for (int tm = 0; tm < 4; ++tm) {
        float4v t = {0.f, 0.f, 0.f, 0.f};
        t = __builtin_amdgcn_mfma_f32_16x16x32_bf16(aqc0, bkf[tm][0], t, 0, 0, 0);
        t = __builtin_amdgcn_mfma_f32_16x16x32_bf16(aqc1, bkf[tm][1], t, 0, 0, 0);
        s[tm] = t;
      }
    }

    // PV(it)
#pragma unroll
    for (int tm = 0; tm < 4; ++tm) {
      const short8 be0 = *reinterpret_cast<const short8*>(
          &Esr[(tm * 16 + l16) * 72 + quad * 8]);
      const short8 be1 = *reinterpret_cast<const short8*>(
          &Esr[(tm * 16 + l16) * 72 + 32 + quad * 8]);
#pragma unroll
      for (int tc = 0; tc < 4; ++tc) {
        acc[tc][tm] = __builtin_amdgcn_mfma_f32_16x16x32_bf16(avc[tc][0], be0, acc[tc][tm], 0, 0, 0);
        acc[tc][tm] = __builtin_amdgcn_mfma_f32_16x16x32_bf16(avc[tc][1], be1, acc[tc][tm], 0, 0, 0);
      }
    }

    // elu(it+1) -> Es[(it+1)&1]; QK results matured during PV
    if (it < 63) {
#pragma unroll
      for (int tm = 0; tm < 4; ++tm) {
        short4v pk;
#pragma unroll
        for (int r = 0; r < 4; ++r) {
          float sv = s[tm][r];
          sv = (sv > 0.f) ? sv : (__expf(sv) - 1.f);
          pk[r] = f2bf(sv);
        }
        *reinterpret_cast<short4v*>(
            &Esw[(tm * 16 + l16) * 72 + wid * 16 + quad * 4]) = pk;
      }
    }
    lds_barrier();   // lgkmcnt-only: Es ordered, global prefetches stay in flight
  };

  for (int it = 0; it < 64; it += 2) {
    seg(it,     avA, avB, aqA0, aqA1, aqB0, aqB1);
    seg(it + 1, avB, avA, aqB0, aqB1, aqA0, aqA1);
  }

  // ---- epilogue: gamma conv via MFMA (INV_N applied here, exact) ----
  // (last seg ended with lgkm-barrier; Es reads done block-wide -> Outs alias ok)
#pragma unroll
  for (int tc = 0; tc < 4; ++tc)
#pragma unroll
    for (int tm = 0; tm < 4; ++tm) {
      short4v pk;
#pragma unroll
      for (int r = 0; r < 4; ++r) pk[r] = f2bf(acc[tc][tm][r] * INV_N);
      *reinterpret_cast<short4v*>(
          &Outs[(tm * 16 + l16) * 264 + wid * 64 + tc * 16 + quad * 4]) = pk;
    }
  __syncthreads();

#pragma unroll
  for (int i = 0; i < 4; ++i)
#pragma unroll
    for (int j = 0; j < 4; ++j) acc[i][j] = float4v{0.f, 0.f, 0.f, 0.f};

  for (int ks8 = 0; ks8 < 8; ++ks8) {
    short8 ag[4];
#pragma unroll
    for (int to = 0; to < 4; ++to)
      ag[to] = *reinterpret_cast<const short8*>(
          &wgb[(size_t)(wid * 64 + to * 16 + l16) * CC + ks8 * 32 + quad * 8]);
    short8 bo[4];
#pragma unroll
    for (int tm = 0; tm < 4; ++tm)
      bo[tm] = *reinterpret_cast<const short8*>(
          &Outs[(tm * 16 + l16) * 264 + ks8 * 32 + quad * 8]);
#pragma unroll
    for (int to = 0; to < 4; ++to)
#pragma unroll
      for (int tm = 0; tm < 4; ++tm)
        acc[to][tm] =
            __builtin_amdgcn_mfma_f32_16x16x32_bf16(ag[to], bo[tm], acc[to][tm], 0, 0, 0);
  }

#pragma unroll
  for (int to = 0; to < 4; ++to) {
#pragma unroll
    for (int r = 0; r < 4; ++r) {
      const int o = wid * 64 + to * 16 + quad * 4 + r;
      const float bgv = bg[o];
#pragma unroll
      for (int tm = 0; tm < 4; ++tm) {
        out[((size_t)b * CC + o) * NN + m0 + tm * 16 + l16] =
            acc[to][tm][r] + bgv;
      }
    }
  }
}

// ---------------------------------------------------------------------------
extern "C" void kernel_launch(void* const* d_in, const int* in_sizes, int n_in,
                              void* d_out, int out_size, void* d_ws,
                              size_t ws_size, hipStream_t stream) {
  const float* x  = (const float*)d_in[0];
  const float* wq = (const float*)d_in[1];
  const float* bq = (const float*)d_in[2];
  const float* wk = (const float*)d_in[3];
  const float* bk = (const float*)d_in[4];
  const float* wv = (const float*)d_in[5];
  const float* bv = (const float*)d_in[6];
  const float* wg = (const float*)d_in[7];
  const float* bg = (const float*)d_in[8];
  float* out = (float*)d_out;

  short* qt  = (short*)d_ws;                     // [B][N][64] bf16, 4 MB
  short* kt  = qt + (size_t)BB * NN * CQ;        // 4 MB
  short* vbf = kt + (size_t)BB * NN * CQ;        // [B][C][N] bf16, 16 MB
  short* wqb = vbf + (size_t)BB * CC * NN;       // bf16 weights, 320 KB total
  short* wkb = wqb + (size_t)CQ * CC;
  short* wvb = wkb + (size_t)CQ * CC;
  short* wgb = wvb + (size_t)CC * CC;

  wconv_kernel<<<dim3(160), 256, 0, stream>>>(wq, wk, wv, wg, wqb, wkb, wvb, wgb);
  qkv_kernel<<<dim3(BB, NN / 64), 256, 0, stream>>>(x, wqb, bq, wkb, bk, wvb, bv,
                                                    qt, kt, vbf);
  attn_kernel<<<dim3(BB, NN / 64), 256, 0, stream>>>(qt, kt, vbf, wgb, bg, out);
}